// Round 1
// baseline (281.107 us; speedup 1.0000x reference)
//
#include <hip/hip_runtime.h>
#include <hip/hip_bf16.h>
#include <stdint.h>

#define TN 4096
#define TD 2048
#define TMARGIN 0.3f

typedef __bf16 bf16x8 __attribute__((ext_vector_type(8)));
typedef float f32x4 __attribute__((ext_vector_type(4)));

// ---------------------------------------------------------------------------
// Kernel 1: per-row prep — fp32 row norm, bf16 hi/lo split, init ap/an.
// grid = TN blocks, 256 threads; thread t handles cols [t*8, t*8+8).
// ---------------------------------------------------------------------------
__global__ __launch_bounds__(256) void prep_kernel(
    const float* __restrict__ X,
    __bf16* __restrict__ H, __bf16* __restrict__ L,
    float* __restrict__ sq, float* __restrict__ ap, unsigned* __restrict__ an_bits)
{
    const int r = blockIdx.x;
    const int t = threadIdx.x;
    const float* xr = X + (size_t)r * TD;

    float4 v0 = ((const float4*)xr)[t * 2 + 0];
    float4 v1 = ((const float4*)xr)[t * 2 + 1];
    float xs[8] = {v0.x, v0.y, v0.z, v0.w, v1.x, v1.y, v1.z, v1.w};

    bf16x8 hv, lv;
    float s = 0.f;
#pragma unroll
    for (int i = 0; i < 8; ++i) {
        float x = xs[i];
        s += x * x;
        __bf16 h = (__bf16)x;          // RNE
        float res = x - (float)h;      // exact
        hv[i] = h;
        lv[i] = (__bf16)res;
    }
    ((bf16x8*)(H + (size_t)r * TD))[t] = hv;
    ((bf16x8*)(L + (size_t)r * TD))[t] = lv;

    // block-reduce s
#pragma unroll
    for (int off = 32; off; off >>= 1) s += __shfl_down(s, off);
    __shared__ float red[4];
    if ((t & 63) == 0) red[t >> 6] = s;
    __syncthreads();
    if (t == 0) {
        sq[r] = red[0] + red[1] + red[2] + red[3];
        ap[r] = 0.0f;                   // dist >= 0, diagonal always positive
        an_bits[r] = 0x7f800000u;       // +inf
    }
}

// ---------------------------------------------------------------------------
// Kernel 2: fused split-GEMM (hh + hl + lh) + dist + hard-mining epilogue.
// 128x128 tile, BK=64, 4 waves (2x2), 16x16x32 bf16 MFMA (m97 structure).
// ---------------------------------------------------------------------------
__device__ inline void gload_lds16(const void* g, void* l) {
    __builtin_amdgcn_global_load_lds(
        (const __attribute__((address_space(1))) uint32_t*)g,
        (__attribute__((address_space(3))) uint32_t*)l, 16, 0, 0);
}

__global__ __launch_bounds__(256, 2) void tile_kernel(
    const __bf16* __restrict__ H, const __bf16* __restrict__ L,
    const float* __restrict__ sq, const int* __restrict__ tg,
    unsigned* __restrict__ ap_bits, unsigned* __restrict__ an_bits)
{
    __shared__ __bf16 lds[4 * 128 * 64];   // Ha | La | Hb | Lb  (64 KB)
    __bf16* Ha = lds;
    __bf16* La = lds + 128 * 64;
    __bf16* Hb = lds + 2 * 128 * 64;
    __bf16* Lb = lds + 3 * 128 * 64;

    const int bj = blockIdx.x, bi = blockIdx.y;
    const int brow = bi * 128, bcol = bj * 128;
    const int tid  = threadIdx.x;
    const int wave = tid >> 6, lane = tid & 63;
    const int wrow = (wave >> 1) * 64, wcol = (wave & 1) * 64;
    const int lr = lane & 15;   // fragment row/col within 16
    const int lk = lane >> 4;   // k-slice 0..3

    f32x4 acc[4][4];
#pragma unroll
    for (int m = 0; m < 4; ++m)
#pragma unroll
        for (int n = 0; n < 4; ++n)
            acc[m][n] = (f32x4){0.f, 0.f, 0.f, 0.f};

    const int srow = tid >> 3;          // 0..31
    const int scol = (tid & 7) * 8;     // element col within BK

    for (int k0 = 0; k0 < TD; k0 += 64) {
        __syncthreads();
#pragma unroll
        for (int it = 0; it < 4; ++it) {
            size_t ga = (size_t)(brow + it * 32 + srow) * TD + k0 + scol;
            size_t gb = (size_t)(bcol + it * 32 + srow) * TD + k0 + scol;
            int lo = it * 2048 + tid * 8;   // element offset in LDS buffer
            gload_lds16(H + ga, Ha + lo);
            gload_lds16(L + ga, La + lo);
            gload_lds16(H + gb, Hb + lo);
            gload_lds16(L + gb, Lb + lo);
        }
        __syncthreads();

#pragma unroll
        for (int ks = 0; ks < 64; ks += 32) {
            bf16x8 ah[4], al[4], bh[4], bl[4];
#pragma unroll
            for (int m = 0; m < 4; ++m) {
                int row = wrow + m * 16 + lr;
                ah[m] = *(const bf16x8*)&Ha[row * 64 + ks + lk * 8];
                al[m] = *(const bf16x8*)&La[row * 64 + ks + lk * 8];
            }
#pragma unroll
            for (int n = 0; n < 4; ++n) {
                int col = wcol + n * 16 + lr;
                bh[n] = *(const bf16x8*)&Hb[col * 64 + ks + lk * 8];
                bl[n] = *(const bf16x8*)&Lb[col * 64 + ks + lk * 8];
            }
#pragma unroll
            for (int m = 0; m < 4; ++m)
#pragma unroll
                for (int n = 0; n < 4; ++n) {
                    acc[m][n] = __builtin_amdgcn_mfma_f32_16x16x32_bf16(ah[m], bh[n], acc[m][n], 0, 0, 0);
                    acc[m][n] = __builtin_amdgcn_mfma_f32_16x16x32_bf16(ah[m], bl[n], acc[m][n], 0, 0, 0);
                    acc[m][n] = __builtin_amdgcn_mfma_f32_16x16x32_bf16(al[m], bh[n], acc[m][n], 0, 0, 0);
                }
        }
    }

    // Epilogue: dist = sqrt(clip(sq_i + sq_j - 2*dot)), masked max/min per row.
    // C/D layout (m89-verified): col = lane&15, row = (lane>>4)*4 + reg.
    float sqj[4]; int tj[4];
#pragma unroll
    for (int n = 0; n < 4; ++n) {
        int j = bcol + wcol + n * 16 + lr;
        sqj[n] = sq[j];
        tj[n]  = tg[j];
    }
#pragma unroll
    for (int m = 0; m < 4; ++m) {
#pragma unroll
        for (int reg = 0; reg < 4; ++reg) {
            int i = brow + wrow + m * 16 + lk * 4 + reg;
            float sqi = sq[i];
            int   ti  = tg[i];
            float pmax = -1.0f;          // max over positives (dist >= 0)
            float pmin = __uint_as_float(0x7f800000u);  // +inf
#pragma unroll
            for (int n = 0; n < 4; ++n) {
                float dot  = acc[m][n][reg];
                float d2   = sqi + sqj[n] - 2.0f * dot;
                float dist = sqrtf(fmaxf(d2, 1e-12f));
                if (ti == tj[n]) pmax = fmaxf(pmax, dist);
                else             pmin = fminf(pmin, dist);
            }
            // reduce across the 16 lanes sharing this row (xor within low 4 bits)
#pragma unroll
            for (int off = 1; off < 16; off <<= 1) {
                pmax = fmaxf(pmax, __shfl_xor(pmax, off));
                pmin = fminf(pmin, __shfl_xor(pmin, off));
            }
            if (lr == 0) {
                if (pmax >= 0.0f) atomicMax(&ap_bits[i], __float_as_uint(pmax));
                atomicMin(&an_bits[i], __float_as_uint(pmin));
            }
        }
    }
}

// ---------------------------------------------------------------------------
// Kernel 3: loss = mean(relu(ap - an + margin)), prec = mean(an > ap).
// ---------------------------------------------------------------------------
__global__ __launch_bounds__(256) void finalize_kernel(
    const float* __restrict__ ap, const float* __restrict__ an, float* __restrict__ out)
{
    const int t = threadIdx.x;
    float ls = 0.f, ps = 0.f;
    for (int i = t; i < TN; i += 256) {
        float a = ap[i], b = an[i];
        ls += fmaxf(a - b + TMARGIN, 0.f);
        ps += (b > a) ? 1.f : 0.f;
    }
#pragma unroll
    for (int off = 32; off; off >>= 1) {
        ls += __shfl_down(ls, off);
        ps += __shfl_down(ps, off);
    }
    __shared__ float r0[4], r1[4];
    if ((t & 63) == 0) { r0[t >> 6] = ls; r1[t >> 6] = ps; }
    __syncthreads();
    if (t == 0) {
        out[0] = (r0[0] + r0[1] + r0[2] + r0[3]) / (float)TN;
        out[1] = (r1[0] + r1[1] + r1[2] + r1[3]) / (float)TN;
    }
}

// ---------------------------------------------------------------------------
extern "C" void kernel_launch(void* const* d_in, const int* in_sizes, int n_in,
                              void* d_out, int out_size, void* d_ws, size_t ws_size,
                              hipStream_t stream)
{
    const float* X  = (const float*)d_in[0];
    const int*   tg = (const int*)d_in[1];
    float* out = (float*)d_out;

    char* ws = (char*)d_ws;
    __bf16* H  = (__bf16*)ws;                                   // 16 MB
    __bf16* L  = (__bf16*)(ws + (size_t)TN * TD * 2);           // 16 MB
    float*  sq = (float*) (ws + (size_t)TN * TD * 4);           // 16 KB
    float*  ap = sq + TN;
    float*  an = ap + TN;

    prep_kernel<<<TN, 256, 0, stream>>>(X, H, L, sq, ap, (unsigned*)an);

    dim3 grid(TN / 128, TN / 128);
    tile_kernel<<<grid, 256, 0, stream>>>(H, L, sq, tg,
                                          (unsigned*)ap, (unsigned*)an);

    finalize_kernel<<<1, 256, 0, stream>>>(ap, an, out);
}

// Round 2
// 261.392 us; speedup vs baseline: 1.0754x; 1.0754x over previous
//
#include <hip/hip_runtime.h>
#include <hip/hip_bf16.h>
#include <stdint.h>

#define TN 4096
#define TD 2048
#define TMARGIN 0.3f
#define BK 32
#define NT (TD / BK)   // 64 K-tiles

typedef __bf16 bf16x8 __attribute__((ext_vector_type(8)));
typedef float f32x4 __attribute__((ext_vector_type(4)));

// ---------------------------------------------------------------------------
// Kernel 1: per-row prep — fp32 row norm, bf16 hi/lo split, init ap/an.
// ---------------------------------------------------------------------------
__global__ __launch_bounds__(256) void prep_kernel(
    const float* __restrict__ X,
    __bf16* __restrict__ H, __bf16* __restrict__ L,
    float* __restrict__ sq, float* __restrict__ ap, unsigned* __restrict__ an_bits)
{
    const int r = blockIdx.x;
    const int t = threadIdx.x;
    const float* xr = X + (size_t)r * TD;

    float4 v0 = ((const float4*)xr)[t * 2 + 0];
    float4 v1 = ((const float4*)xr)[t * 2 + 1];
    float xs[8] = {v0.x, v0.y, v0.z, v0.w, v1.x, v1.y, v1.z, v1.w};

    bf16x8 hv, lv;
    float s = 0.f;
#pragma unroll
    for (int i = 0; i < 8; ++i) {
        float x = xs[i];
        s += x * x;
        __bf16 h = (__bf16)x;          // RNE
        float res = x - (float)h;      // exact
        hv[i] = h;
        lv[i] = (__bf16)res;
    }
    ((bf16x8*)(H + (size_t)r * TD))[t] = hv;
    ((bf16x8*)(L + (size_t)r * TD))[t] = lv;

#pragma unroll
    for (int off = 32; off; off >>= 1) s += __shfl_down(s, off);
    __shared__ float red[4];
    if ((t & 63) == 0) red[t >> 6] = s;
    __syncthreads();
    if (t == 0) {
        sq[r] = red[0] + red[1] + red[2] + red[3];
        ap[r] = 0.0f;                   // diagonal positive has dist 0
        an_bits[r] = 0x7f800000u;       // +inf
    }
}

// ---------------------------------------------------------------------------
// Kernel 2: 256x256-tile 8-wave split-GEMM (hh+hl+lh), 8-phase-style schedule
// (4 phases per BK=32 K-tile), counted vmcnt, raw s_barrier, setprio, and
// both-sides XOR swizzle on the 64B LDS rows (slot ^= (row^row>>2)&3).
// ---------------------------------------------------------------------------
__device__ __forceinline__ void gload_lds16(const void* g, void* l) {
    __builtin_amdgcn_global_load_lds(
        (const __attribute__((address_space(1))) uint32_t*)g,
        (__attribute__((address_space(3))) uint32_t*)l, 16, 0, 0);
}

#define VMCNT2() asm volatile("s_waitcnt vmcnt(2)" ::: "memory")
#define LGKM0()  asm volatile("s_waitcnt lgkmcnt(0)" ::: "memory")
#define BAR()    __builtin_amdgcn_s_barrier()

__global__ __launch_bounds__(512, 2) void tile_kernel(
    const __bf16* __restrict__ H, const __bf16* __restrict__ L,
    const float* __restrict__ sq, const int* __restrict__ tg,
    unsigned* __restrict__ ap_bits, unsigned* __restrict__ an_bits)
{
    // 2 dbuf x {Ha, La, Hb, Lb} x 256 rows x 32 cols bf16 = 128 KiB
    __shared__ __bf16 lds[2][4][256 * BK];

    const int bi = blockIdx.y, bj = blockIdx.x;
    const int brow = bi * 256, bcol = bj * 256;
    const int tid  = threadIdx.x;
    const int lane = tid & 63;
    const int wave = tid >> 6;
    const int wr = wave >> 2;            // 0..1  (M half: rows wr*128..+128)
    const int wc = wave & 3;             // 0..3  (N quarter: cols wc*64..+64)
    const int lr = lane & 15;
    const int lk = lane >> 4;            // 0..3 (k-chunk / acc row group)

    // per-lane constant: physical slot for frag ds_reads (involutive XOR swz)
    const int qs = lk ^ ((lr ^ (lr >> 2)) & 3);

    // staging constants: thread covers load-slots tid and tid+512
    const int srow  = tid >> 2;                      // row 0..127 (+128 for ld1)
    const int sslot = tid & 3;                       // physical slot written
    const int rsw   = (srow ^ (srow >> 2)) & 3;      // same for srow+128
    const int scol0 = (sslot ^ rsw) * 8;             // logical col fetched

    f32x4 acc[8][4];
#pragma unroll
    for (int m = 0; m < 8; ++m)
#pragma unroll
        for (int n = 0; n < 4; ++n)
            acc[m][n] = (f32x4){0.f, 0.f, 0.f, 0.f};

    auto stage = [&](const __bf16* __restrict__ src, int rowbase, int d, int u, int k0) {
        const __bf16* g0 = src + (size_t)(rowbase + srow) * TD + (k0 + scol0);
        const __bf16* g1 = src + (size_t)(rowbase + srow + 128) * TD + (k0 + scol0);
        gload_lds16(g0, &lds[d][u][(size_t)tid * 8]);
        gload_lds16(g1, &lds[d][u][(size_t)(tid + 512) * 8]);
    };

    bf16x8 ah[4], al[4], bh[2], bl[2];

    auto readA = [&](int d, int mh) {
#pragma unroll
        for (int mm = 0; mm < 4; ++mm) {
            int rl = wr * 128 + mh * 64 + mm * 16 + lr;
            int off = rl * BK + qs * 8;
            ah[mm] = *(const bf16x8*)&lds[d][0][off];
            al[mm] = *(const bf16x8*)&lds[d][1][off];
        }
    };
    auto readB = [&](int d, int nh) {
#pragma unroll
        for (int nn = 0; nn < 2; ++nn) {
            int rl = wc * 64 + nh * 32 + nn * 16 + lr;
            int off = rl * BK + qs * 8;
            bh[nn] = *(const bf16x8*)&lds[d][2][off];
            bl[nn] = *(const bf16x8*)&lds[d][3][off];
        }
    };
    auto mma = [&](int mh, int nh) {
        __builtin_amdgcn_s_setprio(1);
#pragma unroll
        for (int mm = 0; mm < 4; ++mm)
#pragma unroll
            for (int nn = 0; nn < 2; ++nn) {
                int m = mh * 4 + mm, n = nh * 2 + nn;
                acc[m][n] = __builtin_amdgcn_mfma_f32_16x16x32_bf16(ah[mm], bh[nn], acc[m][n], 0, 0, 0);
                acc[m][n] = __builtin_amdgcn_mfma_f32_16x16x32_bf16(ah[mm], bl[nn], acc[m][n], 0, 0, 0);
                acc[m][n] = __builtin_amdgcn_mfma_f32_16x16x32_bf16(al[mm], bh[nn], acc[m][n], 0, 0, 0);
            }
        __builtin_amdgcn_s_setprio(0);
    };

    // Prologue: tile0 (all 4 units -> buf0) + tile1 unit0 -> buf1, then wait
    // for tile0 (vmcnt(2) leaves the 2 newest loads in flight).
    stage(H, brow, 0, 0, 0);
    stage(L, brow, 0, 1, 0);
    stage(H, bcol, 0, 2, 0);
    stage(L, bcol, 0, 3, 0);
    stage(H, brow, 1, 0, BK);
    VMCNT2();
    BAR();

    for (int t = 0; t < NT; ++t) {
        const int d = t & 1, dn = d ^ 1;
        const int k1 = (t + 1 < NT) ? (t + 1) * BK : 0;   // clamped: harmless
        const int k2 = (t + 2 < NT) ? (t + 2) * BK : 0;

        // p0: A-mh0 + B-nh0 reads; stage t+1.La
        readA(d, 0);
        readB(d, 0);
        stage(L, brow, dn, 1, k1);
        BAR(); LGKM0();
        mma(0, 0);
        BAR();

        // p1: B-nh1 reads; stage t+1.Hb
        readB(d, 1);
        stage(H, bcol, dn, 2, k1);
        BAR(); LGKM0();
        mma(0, 1);
        BAR();

        // p2: A-mh1 + B-nh0 re-reads; stage t+1.Lb
        readA(d, 1);
        readB(d, 0);
        stage(L, bcol, dn, 3, k1);
        BAR(); LGKM0();
        mma(1, 0);
        BAR();

        // p3: stage t+2.Ha into buf[d] (unit0 free: last read in p2, which is
        // barrier-closed); counted wait drains all of t+1, leaves t+2.Ha in
        // flight. Never vmcnt(0) in the main loop.
        stage(H, brow, d, 0, k2);
        readB(d, 1);
        VMCNT2();
        BAR(); LGKM0();
        mma(1, 1);
        BAR();
    }

    // Epilogue: dist + hard mining. C/D layout: col=lane&15, row=lk*4+reg.
    float sqj[4]; int tj[4];
#pragma unroll
    for (int n = 0; n < 4; ++n) {
        int j = bcol + wc * 64 + n * 16 + lr;
        sqj[n] = sq[j];
        tj[n]  = tg[j];
    }
#pragma unroll
    for (int m = 0; m < 8; ++m) {
#pragma unroll
        for (int reg = 0; reg < 4; ++reg) {
            int i = brow + wr * 128 + m * 16 + lk * 4 + reg;
            float sqi = sq[i];
            int   ti  = tg[i];
            float pmax = -1.0f;
            float pmin = __uint_as_float(0x7f800000u);
#pragma unroll
            for (int n = 0; n < 4; ++n) {
                float d2   = sqi + sqj[n] - 2.0f * acc[m][n][reg];
                float dist = sqrtf(fmaxf(d2, 1e-12f));
                if (ti == tj[n]) pmax = fmaxf(pmax, dist);
                else             pmin = fminf(pmin, dist);
            }
#pragma unroll
            for (int off = 1; off < 16; off <<= 1) {
                pmax = fmaxf(pmax, __shfl_xor(pmax, off));
                pmin = fminf(pmin, __shfl_xor(pmin, off));
            }
            if (lr == 0) {
                if (pmax >= 0.0f) atomicMax(&ap_bits[i], __float_as_uint(pmax));
                atomicMin(&an_bits[i], __float_as_uint(pmin));
            }
        }
    }
}

// ---------------------------------------------------------------------------
// Kernel 3: loss = mean(relu(ap - an + margin)), prec = mean(an > ap).
// ---------------------------------------------------------------------------
__global__ __launch_bounds__(256) void finalize_kernel(
    const float* __restrict__ ap, const float* __restrict__ an, float* __restrict__ out)
{
    const int t = threadIdx.x;
    float ls = 0.f, ps = 0.f;
    for (int i = t; i < TN; i += 256) {
        float a = ap[i], b = an[i];
        ls += fmaxf(a - b + TMARGIN, 0.f);
        ps += (b > a) ? 1.f : 0.f;
    }
#pragma unroll
    for (int off = 32; off; off >>= 1) {
        ls += __shfl_down(ls, off);
        ps += __shfl_down(ps, off);
    }
    __shared__ float r0[4], r1[4];
    if ((t & 63) == 0) { r0[t >> 6] = ls; r1[t >> 6] = ps; }
    __syncthreads();
    if (t == 0) {
        out[0] = (r0[0] + r0[1] + r0[2] + r0[3]) / (float)TN;
        out[1] = (r1[0] + r1[1] + r1[2] + r1[3]) / (float)TN;
    }
}

// ---------------------------------------------------------------------------
extern "C" void kernel_launch(void* const* d_in, const int* in_sizes, int n_in,
                              void* d_out, int out_size, void* d_ws, size_t ws_size,
                              hipStream_t stream)
{
    const float* X  = (const float*)d_in[0];
    const int*   tg = (const int*)d_in[1];
    float* out = (float*)d_out;

    char* ws = (char*)d_ws;
    __bf16* Hp = (__bf16*)ws;                                   // 16 MB
    __bf16* Lp = (__bf16*)(ws + (size_t)TN * TD * 2);           // 16 MB
    float*  sq = (float*) (ws + (size_t)TN * TD * 4);           // 16 KB
    float*  ap = sq + TN;
    float*  an = ap + TN;

    prep_kernel<<<TN, 256, 0, stream>>>(X, Hp, Lp, sq, ap, (unsigned*)an);

    dim3 grid(TN / 4, TN / 4);   // placeholder, fixed below
    dim3 grid2(4096 / 256, 4096 / 256);   // 16 x 16 = 256 blocks
    tile_kernel<<<grid2, 512, 0, stream>>>(Hp, Lp, sq, tg,
                                           (unsigned*)ap, (unsigned*)an);

    finalize_kernel<<<1, 256, 0, stream>>>(ap, an, out);
}

// Round 3
// 255.580 us; speedup vs baseline: 1.0999x; 1.0227x over previous
//
#include <hip/hip_runtime.h>
#include <hip/hip_bf16.h>
#include <stdint.h>

#define TN 4096
#define TD 2048
#define TMARGIN 0.3f
#define BK 32
#define NT (TD / BK)   // 64 K-tiles

typedef __bf16 bf16x8 __attribute__((ext_vector_type(8)));
typedef float f32x4 __attribute__((ext_vector_type(4)));

// ---------------------------------------------------------------------------
// Kernel 1: per-row prep — fp32 row norm, bf16 hi/lo split, init ap/an.
// ---------------------------------------------------------------------------
__global__ __launch_bounds__(256) void prep_kernel(
    const float* __restrict__ X,
    __bf16* __restrict__ H, __bf16* __restrict__ L,
    float* __restrict__ sq, float* __restrict__ ap, unsigned* __restrict__ an_bits)
{
    const int r = blockIdx.x;
    const int t = threadIdx.x;
    const float* xr = X + (size_t)r * TD;

    float4 v0 = ((const float4*)xr)[t * 2 + 0];
    float4 v1 = ((const float4*)xr)[t * 2 + 1];
    float xs[8] = {v0.x, v0.y, v0.z, v0.w, v1.x, v1.y, v1.z, v1.w};

    bf16x8 hv, lv;
    float s = 0.f;
#pragma unroll
    for (int i = 0; i < 8; ++i) {
        float x = xs[i];
        s += x * x;
        __bf16 h = (__bf16)x;          // RNE
        float res = x - (float)h;      // exact
        hv[i] = h;
        lv[i] = (__bf16)res;
    }
    ((bf16x8*)(H + (size_t)r * TD))[t] = hv;
    ((bf16x8*)(L + (size_t)r * TD))[t] = lv;

#pragma unroll
    for (int off = 32; off; off >>= 1) s += __shfl_down(s, off);
    __shared__ float red[4];
    if ((t & 63) == 0) red[t >> 6] = s;
    __syncthreads();
    if (t == 0) {
        sq[r] = red[0] + red[1] + red[2] + red[3];
        ap[r] = 0.0f;                   // diagonal positive has dist 0
        an_bits[r] = 0x7f800000u;       // +inf
    }
}

// ---------------------------------------------------------------------------
// Kernel 2: 256x256 tile, 8 waves, 3-pass split-GEMM with pass-per-phase
// schedule: 3 phases/K-tile (hh, hl, lh), one stage-unit per phase,
// uniform counted vmcnt(6) (3 units in flight), data drained one barrier
// before first read. 32 independent MFMAs per phase.
// ---------------------------------------------------------------------------
__device__ __forceinline__ void gload_lds16(const void* g, void* l) {
    __builtin_amdgcn_global_load_lds(
        (const __attribute__((address_space(1))) uint32_t*)g,
        (__attribute__((address_space(3))) uint32_t*)l, 16, 0, 0);
}

#define VMCNT6() asm volatile("s_waitcnt vmcnt(6)" ::: "memory")
#define LGKM0()  asm volatile("s_waitcnt lgkmcnt(0)" ::: "memory")
#define BAR()    __builtin_amdgcn_s_barrier()

__global__ __launch_bounds__(512, 1) void tile_kernel(
    const __bf16* __restrict__ H, const __bf16* __restrict__ L,
    const float* __restrict__ sq, const int* __restrict__ tg,
    unsigned* __restrict__ ap_bits, unsigned* __restrict__ an_bits)
{
    // 2 dbuf x {Ha, La, Hb, Lb} x 256 rows x 32 cols bf16 = 128 KiB
    __shared__ __bf16 lds[2][4][256 * BK];

    const int bi = blockIdx.y, bj = blockIdx.x;
    const int brow = bi * 256, bcol = bj * 256;
    const int tid  = threadIdx.x;
    const int lane = tid & 63;
    const int wave = tid >> 6;
    const int wr = wave >> 2;            // 0..1  (M half: rows wr*128..+128)
    const int wc = wave & 3;             // 0..3  (N quarter: cols wc*64..+64)
    const int lr = lane & 15;
    const int lk = lane >> 4;            // 0..3

    // physical slot for frag ds_reads (involutive XOR swizzle, round-2-verified)
    const int qs = lk ^ ((lr ^ (lr >> 2)) & 3);

    // staging: thread covers load-slots tid and tid+512
    const int srow  = tid >> 2;                      // row 0..127 (+128 for ld1)
    const int sslot = tid & 3;                       // physical slot written
    const int rsw   = (srow ^ (srow >> 2)) & 3;      // swz(srow) == swz(srow+128)
    const int scol0 = (sslot ^ rsw) * 8;             // logical col fetched

    f32x4 acc[8][4];
#pragma unroll
    for (int m = 0; m < 8; ++m)
#pragma unroll
        for (int n = 0; n < 4; ++n)
            acc[m][n] = (f32x4){0.f, 0.f, 0.f, 0.f};

    auto stage = [&](const __bf16* __restrict__ src, int rowbase, int d, int u, int k0) {
        const __bf16* g0 = src + (size_t)(rowbase + srow) * TD + (k0 + scol0);
        const __bf16* g1 = src + (size_t)(rowbase + srow + 128) * TD + (k0 + scol0);
        gload_lds16(g0, &lds[d][u][(size_t)tid * 8]);
        gload_lds16(g1, &lds[d][u][(size_t)(tid + 512) * 8]);
    };

    bf16x8 ah[8], al[8], bh[4], bl[4];

    auto readAH = [&](int d) {
#pragma unroll
        for (int m = 0; m < 8; ++m) {
            int off = (wr * 128 + m * 16 + lr) * BK + qs * 8;
            ah[m] = *(const bf16x8*)&lds[d][0][off];
        }
    };
    auto readAL = [&](int d) {
#pragma unroll
        for (int m = 0; m < 8; ++m) {
            int off = (wr * 128 + m * 16 + lr) * BK + qs * 8;
            al[m] = *(const bf16x8*)&lds[d][1][off];
        }
    };
    auto readBH = [&](int d) {
#pragma unroll
        for (int n = 0; n < 4; ++n) {
            int off = (wc * 64 + n * 16 + lr) * BK + qs * 8;
            bh[n] = *(const bf16x8*)&lds[d][2][off];
        }
    };
    auto readBL = [&](int d) {
#pragma unroll
        for (int n = 0; n < 4; ++n) {
            int off = (wc * 64 + n * 16 + lr) * BK + qs * 8;
            bl[n] = *(const bf16x8*)&lds[d][3][off];
        }
    };

    auto mma_hh = [&]() {
        __builtin_amdgcn_s_setprio(1);
#pragma unroll
        for (int m = 0; m < 8; ++m)
#pragma unroll
            for (int n = 0; n < 4; ++n)
                acc[m][n] = __builtin_amdgcn_mfma_f32_16x16x32_bf16(ah[m], bh[n], acc[m][n], 0, 0, 0);
        __builtin_amdgcn_s_setprio(0);
    };
    auto mma_hl = [&]() {
        __builtin_amdgcn_s_setprio(1);
#pragma unroll
        for (int m = 0; m < 8; ++m)
#pragma unroll
            for (int n = 0; n < 4; ++n)
                acc[m][n] = __builtin_amdgcn_mfma_f32_16x16x32_bf16(ah[m], bl[n], acc[m][n], 0, 0, 0);
        __builtin_amdgcn_s_setprio(0);
    };
    auto mma_lh = [&]() {
        __builtin_amdgcn_s_setprio(1);
#pragma unroll
        for (int m = 0; m < 8; ++m)
#pragma unroll
            for (int n = 0; n < 4; ++n)
                acc[m][n] = __builtin_amdgcn_mfma_f32_16x16x32_bf16(al[m], bh[n], acc[m][n], 0, 0, 0);
        __builtin_amdgcn_s_setprio(0);
    };

    // Prologue: fill pipeline. After vmcnt(6): Ha(0),Hb(0) drained;
    // [Lb(0), La(0), Ha(1)] in flight == steady-state entry condition.
    stage(H, brow, 0, 0, 0);    // Ha(0)
    stage(H, bcol, 0, 2, 0);    // Hb(0)
    stage(L, bcol, 0, 3, 0);    // Lb(0)
    stage(L, brow, 0, 1, 0);    // La(0)
    stage(H, brow, 1, 0, BK);   // Ha(1)
    VMCNT6();
    BAR();

    for (int t = 0; t < NT; ++t) {
        const int d = t & 1, dn = d ^ 1;
        const int k1 = ((t + 1 < NT) ? t + 1 : NT - 1) * BK;
        const int k2 = ((t + 2 < NT) ? t + 2 : NT - 1) * BK;

        // p0 (hh): reads Ha(t),Hb(t) — drained at (t-1).p2.
        readAH(d);
        readBH(d);
        stage(H, bcol, dn, 2, k1);            // Hb(t+1)
        VMCNT6();                             // drains Lb(t)  (needed p1)
        BAR(); LGKM0();
        mma_hh();
        BAR();

        // p1 (hl): reads Lb(t) — drained at t.p0.
        readBL(d);
        stage(L, bcol, dn, 3, k1);            // Lb(t+1)
        VMCNT6();                             // drains La(t)  (needed p2)
        BAR(); LGKM0();
        mma_hl();
        BAR();

        // p2 (lh): reads La(t) — drained at t.p1.
        readAL(d);
        stage(L, brow, dn, 1, k1);            // La(t+1)
        stage(H, brow, d,  0, k2);            // Ha(t+2)
        VMCNT6();                             // drains Ha(t+1), Hb(t+1)
        BAR(); LGKM0();
        mma_lh();
        BAR();
    }

    // Epilogue: dist + hard mining. C/D layout: col=lane&15, row=lk*4+reg.
    float sqj[4]; int tj[4];
#pragma unroll
    for (int n = 0; n < 4; ++n) {
        int j = bcol + wc * 64 + n * 16 + lr;
        sqj[n] = sq[j];
        tj[n]  = tg[j];
    }
#pragma unroll
    for (int m = 0; m < 8; ++m) {
#pragma unroll
        for (int reg = 0; reg < 4; ++reg) {
            int i = brow + wr * 128 + m * 16 + lk * 4 + reg;
            float sqi = sq[i];
            int   ti  = tg[i];
            float pmax = -1.0f;
            float pmin = __uint_as_float(0x7f800000u);
#pragma unroll
            for (int n = 0; n < 4; ++n) {
                float d2   = sqi + sqj[n] - 2.0f * acc[m][n][reg];
                float dist = sqrtf(fmaxf(d2, 1e-12f));
                if (ti == tj[n]) pmax = fmaxf(pmax, dist);
                else             pmin = fminf(pmin, dist);
            }
#pragma unroll
            for (int off = 1; off < 16; off <<= 1) {
                pmax = fmaxf(pmax, __shfl_xor(pmax, off));
                pmin = fminf(pmin, __shfl_xor(pmin, off));
            }
            if (lr == 0) {
                if (pmax >= 0.0f) atomicMax(&ap_bits[i], __float_as_uint(pmax));
                atomicMin(&an_bits[i], __float_as_uint(pmin));
            }
        }
    }
}

// ---------------------------------------------------------------------------
// Kernel 3: loss = mean(relu(ap - an + margin)), prec = mean(an > ap).
// ---------------------------------------------------------------------------
__global__ __launch_bounds__(256) void finalize_kernel(
    const float* __restrict__ ap, const float* __restrict__ an, float* __restrict__ out)
{
    const int t = threadIdx.x;
    float ls = 0.f, ps = 0.f;
    for (int i = t; i < TN; i += 256) {
        float a = ap[i], b = an[i];
        ls += fmaxf(a - b + TMARGIN, 0.f);
        ps += (b > a) ? 1.f : 0.f;
    }
#pragma unroll
    for (int off = 32; off; off >>= 1) {
        ls += __shfl_down(ls, off);
        ps += __shfl_down(ps, off);
    }
    __shared__ float r0[4], r1[4];
    if ((t & 63) == 0) { r0[t >> 6] = ls; r1[t >> 6] = ps; }
    __syncthreads();
    if (t == 0) {
        out[0] = (r0[0] + r0[1] + r0[2] + r0[3]) / (float)TN;
        out[1] = (r1[0] + r1[1] + r1[2] + r1[3]) / (float)TN;
    }
}

// ---------------------------------------------------------------------------
extern "C" void kernel_launch(void* const* d_in, const int* in_sizes, int n_in,
                              void* d_out, int out_size, void* d_ws, size_t ws_size,
                              hipStream_t stream)
{
    const float* X  = (const float*)d_in[0];
    const int*   tg = (const int*)d_in[1];
    float* out = (float*)d_out;

    char* ws = (char*)d_ws;
    __bf16* Hp = (__bf16*)ws;                                   // 16 MB
    __bf16* Lp = (__bf16*)(ws + (size_t)TN * TD * 2);           // 16 MB
    float*  sq = (float*) (ws + (size_t)TN * TD * 4);           // 16 KB
    float*  ap = sq + TN;
    float*  an = ap + TN;

    prep_kernel<<<TN, 256, 0, stream>>>(X, Hp, Lp, sq, ap, (unsigned*)an);

    dim3 grid(4096 / 256, 4096 / 256);   // 16 x 16 = 256 blocks
    tile_kernel<<<grid, 512, 0, stream>>>(Hp, Lp, sq, tg,
                                          (unsigned*)ap, (unsigned*)an);

    finalize_kernel<<<1, 256, 0, stream>>>(ap, an, out);
}